// Round 15
// baseline (37.757 us; speedup 1.0000x reference)
//
#include <hip/hip_runtime.h>

#define B 8
#define K 8
#define H 384
#define W 384
#define HW (H*W)                 // 147456 pixels per batch
#define NCPP 16                  // chunks per plane-pair column (2304 groups each, same as R10)
#define GROUPS_PER_B (HW/4)      // 36864 float4-groups per batch
#define MT_FLOATS ((size_t)B*4*GROUPS_PER_B*8)   // pair-interleaved mask copy: 37.75 MB
#define WSP_OFF MT_FLOATS                        // partials offset (floats)

typedef float f32x4 __attribute__((ext_vector_type(4)));

__device__ __forceinline__ float4 ntload4(const float* p) {
    f32x4 v = __builtin_nontemporal_load((const f32x4*)p);
    return make_float4(v.x, v.y, v.z, v.w);
}

__device__ __forceinline__ void euler2mat(float ax, float ay, float az, float R[9]) {
    float cx = cosf(ax), sx = sinf(ax);
    float cy = cosf(ay), sy = sinf(ay);
    float cz = cosf(az), sz = sinf(az);
    // R = xmat @ ymat @ zmat
    R[0] = cy*cz;              R[1] = -cy*sz;             R[2] = sy;
    R[3] = cx*sz + sx*sy*cz;   R[4] = cx*cz - sx*sy*sz;   R[5] = -sx*cy;
    R[6] = sx*sz - cx*sy*cz;   R[7] = sx*cz + cx*sy*sz;   R[8] = cx*cy;
}

// ---------------- Stage A: 2-plane read (k_reduce shape) + pair-interleaved
// transpose write + fused reduction. Per-accumulator add order identical to the
// proven k_reduce -> p_k bit-exact. ----------------
__global__ __launch_bounds__(256) void k_trans(const float* __restrict__ mask,
                                               const float* __restrict__ depth,
                                               float* __restrict__ ws) {
    const int chunk = blockIdx.x, kp = blockIdx.y, b = blockIdx.z;
    const int tid = threadIdx.x;

    const float* mA = mask + ((size_t)(b*K + 2*kp)) * HW;
    const float* mB = mA + HW;
    const float4* d4 = (const float4*)(depth + (size_t)b * HW);
    float4* mt = (float4*)ws + (size_t)(b*4 + kp) * GROUPS_PER_B * 2;

    float a0=0.f,a1=0.f,a2=0.f,a3=0.f;       // plane 2kp
    float c0=0.f,c1=0.f,c2=0.f,c3=0.f;       // plane 2kp+1
    const float inv = 2.f / W;

#pragma unroll
    for (int r = 0; r < 9; ++r) {
        int g = (chunk * 9 + r) * 256 + tid;  // float4-group in [0, 36864)
        float4 va = ntload4(mA + (size_t)g * 4);
        float4 vb = ntload4(mB + (size_t)g * 4);
        float4 dv = d4[g];
        int i0 = g * 4;
        int h = i0 / W;
        int w0 = i0 - h * W;
        float py = 2.f * (h + 0.5f) * (1.f / H) - 1.f;
        float px0 = 2.f * (w0 + 0.5f) * (1.f / W) - 1.f;
        float ma[4] = {va.x, va.y, va.z, va.w};
        float mb[4] = {vb.x, vb.y, vb.z, vb.w};
        float dd[4] = {dv.x, dv.y, dv.z, dv.w};
#pragma unroll
        for (int j = 0; j < 4; ++j) {
            float px = px0 + j * inv;
            float t = ma[j] * dd[j];
            a0 += ma[j]; a1 += t * px; a2 += t * py; a3 += t;
            float u = mb[j] * dd[j];
            c0 += mb[j]; c1 += u * px; c2 += u * py; c3 += u;
        }
        // pair-interleaved copy: contiguous 2 KB per wave, full lines
        mt[(size_t)g * 2 + 0] = va;
        mt[(size_t)g * 2 + 1] = vb;
    }

    for (int off = 32; off > 0; off >>= 1) {
        a0 += __shfl_down(a0, off); a1 += __shfl_down(a1, off);
        a2 += __shfl_down(a2, off); a3 += __shfl_down(a3, off);
        c0 += __shfl_down(c0, off); c1 += __shfl_down(c1, off);
        c2 += __shfl_down(c2, off); c3 += __shfl_down(c3, off);
    }
    __shared__ float sd[32];
    int lane = tid & 63, wid = tid >> 6;
    if (lane == 0) {
        sd[wid*8+0]=a0; sd[wid*8+1]=a1; sd[wid*8+2]=a2; sd[wid*8+3]=a3;
        sd[wid*8+4]=c0; sd[wid*8+5]=c1; sd[wid*8+6]=c2; sd[wid*8+7]=c3;
    }
    __syncthreads();
    if (tid < 8) {
        float v = sd[tid] + sd[8 + tid] + sd[16 + tid] + sd[24 + tid];
        // partials layout per b: [kp][chunk][lsb*4+comp] = 512 floats
        ws[WSP_OFF + (((size_t)(b*4 + kp)) * NCPP + chunk) * 8 + tid] = v;
    }
}

// ---------------- Stage B+C: params fold + flow from the pair-interleaved copy ----------------
__global__ __launch_bounds__(256) void k_flow2(const float* __restrict__ depth,
                                               const float* __restrict__ T,
                                               const float* __restrict__ Tc,
                                               const float* __restrict__ ws,
                                               float* __restrict__ out) {
    const int b = blockIdx.y;
    const int tid = threadIdx.x;

    __shared__ float sP[512];
    __shared__ float s32[32];
    __shared__ float sp[108];

    const int g = blockIdx.x * 256 + tid;     // [0, 36864)
    const int i0 = g * 4;
    float4 dv = ((const float4*)(depth + (size_t)b * HW))[g];

    // 4 pair-streams, 32 B contiguous per thread per stream; pf[k] == mask plane k.
    float4 pf[8];
#pragma unroll
    for (int kp = 0; kp < 4; ++kp) {
        const float4* mt = (const float4*)ws + (size_t)(b*4 + kp) * GROUPS_PER_B * 2;
        pf[kp*2 + 0] = mt[(size_t)g*2 + 0];
        pf[kp*2 + 1] = mt[(size_t)g*2 + 1];
    }

    // ---- stage partials (512 floats) and fold in proven ch-ascending order ----
    if (tid < 128)
        ((float4*)sP)[tid] = ((const float4*)(ws + WSP_OFF + (size_t)b * 512))[tid];
    __syncthreads();

    if (tid < 32) {
        int k = tid >> 2, comp = tid & 3;
        int kp = k >> 1, lsb = k & 1;
        float s = 0.f;
#pragma unroll
        for (int ch = 0; ch < NCPP; ++ch) s += sP[kp*128 + ch*8 + lsb*4 + comp];
        s32[tid] = s;
    }
    __syncthreads();

    if (tid < 8) {
        int k = tid;
        float mass = s32[k*4 + 0] + 1e-6f;
        float p0 = s32[k*4 + 1] / mass;
        float p1 = s32[k*4 + 2] / mass;
        float p2 = s32[k*4 + 3] / mass;
        const float* Tk = T + (b*K + k) * 6;
        float R[9];
        euler2mat(Tk[3], Tk[4], Tk[5], R);
        float Rp0 = R[0]*p0 + R[1]*p1 + R[2]*p2;
        float Rp1 = R[3]*p0 + R[4]*p1 + R[5]*p2;
        float Rp2 = R[6]*p0 + R[7]*p1 + R[8]*p2;
        float* o = sp + k * 12;
        o[0] = R[0] - 1.f; o[1] = R[1];       o[2] = R[2];
        o[3] = R[3];       o[4] = R[4] - 1.f; o[5] = R[5];
        o[6] = R[6];       o[7] = R[7];       o[8] = R[8] - 1.f;
        o[9]  = p0 + Tk[0] - Rp0;
        o[10] = p1 + Tk[1] - Rp1;
        o[11] = p2 + Tk[2] - Rp2;
    } else if (tid == 8) {
        const float* Tb = Tc + b * 9;
        float R[9];
        euler2mat(Tb[3], Tb[4], Tb[5], R);
        float pc0 = Tb[6], pc1 = Tb[7], pc2 = Tb[8];
        float* o = sp + 96;
#pragma unroll
        for (int i = 0; i < 9; ++i) o[i] = R[i];
        o[9]  = pc0 + Tb[0] - (R[0]*pc0 + R[1]*pc1 + R[2]*pc2);
        o[10] = pc1 + Tb[1] - (R[3]*pc0 + R[4]*pc1 + R[5]*pc2);
        o[11] = pc2 + Tb[2] - (R[6]*pc0 + R[7]*pc1 + R[8]*pc2);
    }
    __syncthreads();

    // ---- per-pixel transform (arithmetic identical to all passing rounds) ----
    int h = i0 / W;
    int w0 = i0 - h * W;
    float py = 2.f * (h + 0.5f) * (1.f / H) - 1.f;
    const float inv = 2.f / W;
    float px0 = 2.f * (w0 + 0.5f) * (1.f / W) - 1.f;

    float dd[4] = {dv.x, dv.y, dv.z, dv.w};
    float res[8];
#pragma unroll
    for (int j = 0; j < 4; ++j) {
        float px = px0 + j * inv;
        float d = dd[j];
        float wx = d * px, wy = d * py, wz = d;
        float ax = wx, ay = wy, az = wz;
#pragma unroll
        for (int k = 0; k < K; ++k) {
            const float* P = sp + k * 12;
            float m = (j == 0) ? pf[k].x : (j == 1) ? pf[k].y : (j == 2) ? pf[k].z : pf[k].w;
            float rx = P[0]*wx + P[1]*wy + P[2]*wz + P[9];
            float ry = P[3]*wx + P[4]*wy + P[5]*wz + P[10];
            float rz = P[6]*wx + P[7]*wy + P[8]*wz + P[11];
            ax += m * rx; ay += m * ry; az += m * rz;
        }
        const float* C = sp + 96;
        float ox = C[0]*ax + C[1]*ay + C[2]*az + C[9];
        float oy = C[3]*ax + C[4]*ay + C[5]*az + C[10];
        float oz = C[6]*ax + C[7]*ay + C[8]*az + C[11];
        res[j*2 + 0] = ox / oz - px;
        res[j*2 + 1] = oy / oz - py;
    }

    f32x4* o4 = (f32x4*)(out + ((size_t)b * HW + i0) * 2);
    f32x4 v0 = {res[0], res[1], res[2], res[3]};
    f32x4 v1 = {res[4], res[5], res[6], res[7]};
    __builtin_nontemporal_store(v0, o4);
    __builtin_nontemporal_store(v1, o4 + 1);
}

extern "C" void kernel_launch(void* const* d_in, const int* in_sizes, int n_in,
                              void* d_out, int out_size, void* d_ws, size_t ws_size,
                              hipStream_t stream) {
    // inputs: im (unused), mask, depth, T, Tc — all float32
    const float* mask  = (const float*)d_in[1];
    const float* depth = (const float*)d_in[2];
    const float* T     = (const float*)d_in[3];
    const float* Tc    = (const float*)d_in[4];
    float* ws  = (float*)d_ws;
    float* out = (float*)d_out;

    k_trans<<<dim3(NCPP, 4, B), 256, 0, stream>>>(mask, depth, ws);
    k_flow2<<<dim3(GROUPS_PER_B / 256, B), 256, 0, stream>>>(depth, T, Tc, ws, out);
}

// Round 16
// 27.128 us; speedup vs baseline: 1.3918x; 1.3918x over previous
//
#include <hip/hip_runtime.h>

#define B 8
#define K 8
#define H 384
#define W 384
#define HW (H*W)                 // 147456 pixels per batch
#define NCPP 16                  // chunks per (b,k) plane in stage A
#define GROUPS_PER_B (HW/4)      // 36864 float4-groups per batch
#define WS_PK (B*K*NCPP*4)       // 4096: params offset (R2 layout)
#define WS_PB (WS_PK + B*K*12)   // 4864: camera params offset

typedef float f32x4 __attribute__((ext_vector_type(4)));

__device__ __forceinline__ float4 ntload4(const float* p) {
    f32x4 v = __builtin_nontemporal_load((const f32x4*)p);
    return make_float4(v.x, v.y, v.z, v.w);
}

__device__ __forceinline__ void euler2mat(float ax, float ay, float az, float R[9]) {
    float cx = cosf(ax), sx = sinf(ax);
    float cy = cosf(ay), sy = sinf(ay);
    float cz = cosf(az), sz = sinf(az);
    // R = xmat @ ymat @ zmat
    R[0] = cy*cz;              R[1] = -cy*sz;             R[2] = sy;
    R[3] = cx*sz + sx*sy*cz;   R[4] = cx*cz - sx*sy*sz;   R[5] = -sx*cy;
    R[6] = sx*sz - cx*sy*cz;   R[7] = sx*cz + cx*sy*sz;   R[8] = cx*cy;
}

// ---------------- Stage A: byte-identical to round 10 (~7.2 us, at roofline) ----------------
__global__ __launch_bounds__(256) void k_reduce(const float* __restrict__ mask,
                                                const float* __restrict__ depth,
                                                float* __restrict__ ws) {
    const int chunk = blockIdx.x, k = blockIdx.y, b = blockIdx.z;
    const int tid = threadIdx.x;

    const float* mbase = mask + ((size_t)(b*K + k)) * HW;
    const float4* d4 = (const float4*)(depth + (size_t)b * HW);

    float s0 = 0.f, s1 = 0.f, s2 = 0.f, s3 = 0.f;
    const float inv = 2.f / W;

#pragma unroll
    for (int r = 0; r < 9; ++r) {
        int g = (chunk * 9 + r) * 256 + tid;
        float4 mv = ntload4(mbase + (size_t)g * 4);
        float4 dv = d4[g];
        int i0 = g * 4;
        int h = i0 / W;
        int w0 = i0 - h * W;
        float py = 2.f * (h + 0.5f) * (1.f / H) - 1.f;
        float px0 = 2.f * (w0 + 0.5f) * (1.f / W) - 1.f;
        float mm[4] = {mv.x, mv.y, mv.z, mv.w};
        float dd[4] = {dv.x, dv.y, dv.z, dv.w};
#pragma unroll
        for (int j = 0; j < 4; ++j) {
            float m = mm[j];
            float t = m * dd[j];
            float px = px0 + j * inv;
            s0 += m; s1 += t * px; s2 += t * py; s3 += t;
        }
    }

    for (int off = 32; off > 0; off >>= 1) {
        s0 += __shfl_down(s0, off);
        s1 += __shfl_down(s1, off);
        s2 += __shfl_down(s2, off);
        s3 += __shfl_down(s3, off);
    }
    __shared__ float sd[16];
    int lane = tid & 63, wid = tid >> 6;
    if (lane == 0) { sd[wid*4+0]=s0; sd[wid*4+1]=s1; sd[wid*4+2]=s2; sd[wid*4+3]=s3; }
    __syncthreads();
    if (tid < 4) {
        float v = sd[tid] + sd[4 + tid] + sd[8 + tid] + sd[12 + tid];
        ws[(((b*K + k) * NCPP) + chunk) * 4 + tid] = v;
    }
}

// ---------------- Stage B: proven round-2 k_params (bit-exact fold + trig) ----------------
__global__ void k_params(const float* __restrict__ T, const float* __restrict__ Tc,
                         float* __restrict__ ws) {
    int t = threadIdx.x;
    if (t < 64) {
        float s0 = 0.f, s1 = 0.f, s2 = 0.f, s3 = 0.f;
        for (int ch = 0; ch < NCPP; ++ch) {
            const float* src = ws + (t * NCPP + ch) * 4;
            s0 += src[0]; s1 += src[1]; s2 += src[2]; s3 += src[3];
        }
        float mass = s0 + 1e-6f;
        float p0 = s1 / mass, p1 = s2 / mass, p2 = s3 / mass;
        const float* Tk = T + t * 6;
        float R[9];
        euler2mat(Tk[3], Tk[4], Tk[5], R);
        float* o = ws + WS_PK + t * 12;
        o[0] = R[0] - 1.f; o[1] = R[1];       o[2] = R[2];
        o[3] = R[3];       o[4] = R[4] - 1.f; o[5] = R[5];
        o[6] = R[6];       o[7] = R[7];       o[8] = R[8] - 1.f;
        o[9]  = p0 + Tk[0] - (R[0]*p0 + R[1]*p1 + R[2]*p2);
        o[10] = p1 + Tk[1] - (R[3]*p0 + R[4]*p1 + R[5]*p2);
        o[11] = p2 + Tk[2] - (R[6]*p0 + R[7]*p1 + R[8]*p2);
    }
    if (t < 8) {
        const float* Tb = Tc + t * 9;
        float R[9];
        euler2mat(Tb[3], Tb[4], Tb[5], R);
        float pc0 = Tb[6], pc1 = Tb[7], pc2 = Tb[8];
        float* o = ws + WS_PB + t * 12;
#pragma unroll
        for (int i = 0; i < 9; ++i) o[i] = R[i];
        o[9]  = pc0 + Tb[0] - (R[0]*pc0 + R[1]*pc1 + R[2]*pc2);
        o[10] = pc1 + Tb[1] - (R[3]*pc0 + R[4]*pc1 + R[5]*pc2);
        o[11] = pc2 + Tb[2] - (R[6]*pc0 + R[7]*pc1 + R[8]*pc2);
    }
}

// ---------------- Stage C: long-run k-outer flow ----------------
// 256 blocks (1/CU), 384 threads, each thread owns 3 fixed pixel-groups.
// k-loop OUTER: the block reads plane k's 18 KB window as one contiguous run,
// then jumps to plane k+1 (k_reduce-shaped request stream). Accumulators in
// registers; per-pixel add order k-ascending -> bit-exact with all passing
// rounds. No barriers/sched-fences in the loop: compiler pipelines the 24
// independent loads.
__global__ __launch_bounds__(384) void k_flow3(const float* __restrict__ mask,
                                               const float* __restrict__ depth,
                                               const float* __restrict__ ws,
                                               float* __restrict__ out) {
    const int b = blockIdx.y;
    const int wdw = blockIdx.x;                 // window in [0,32)
    const int tid = threadIdx.x;

    __shared__ float sp[108];
    if (tid < 96) sp[tid] = ws[WS_PK + b * 96 + tid];
    else if (tid < 108) sp[tid] = ws[WS_PB + b * 12 + (tid - 96)];

    int g[3];
    float4 dvv[3];
#pragma unroll
    for (int i = 0; i < 3; ++i) {
        g[i] = wdw * 1152 + i * 384 + tid;      // three groups, 384 apart
        dvv[i] = ((const float4*)(depth + (size_t)b * HW))[g[i]];
    }
    __syncthreads();

    const float inv = 2.f / W;
    float pyv[3], pxj[3][4], dd[3][4];
    float wx[3][4], wy[3][4], wz[3][4], ax[3][4], ay[3][4], az[3][4];
#pragma unroll
    for (int i = 0; i < 3; ++i) {
        int h = g[i] / 96;
        int w0 = (g[i] - h * 96) * 4;
        pyv[i] = 2.f * (h + 0.5f) * (1.f / H) - 1.f;
        float px0 = 2.f * (w0 + 0.5f) * (1.f / W) - 1.f;
        float d4a[4] = {dvv[i].x, dvv[i].y, dvv[i].z, dvv[i].w};
#pragma unroll
        for (int j = 0; j < 4; ++j) {
            pxj[i][j] = px0 + j * inv;
            dd[i][j] = d4a[j];
            wx[i][j] = d4a[j] * pxj[i][j];
            wy[i][j] = d4a[j] * pyv[i];
            wz[i][j] = d4a[j];
            ax[i][j] = wx[i][j]; ay[i][j] = wy[i][j]; az[i][j] = wz[i][j];
        }
    }

    const float* mb = mask + ((size_t)b * K) * HW;
#pragma unroll
    for (int k = 0; k < K; ++k) {
        const float* P = sp + k * 12;
        float4 mv[3];
#pragma unroll
        for (int i = 0; i < 3; ++i)
            mv[i] = ntload4(mb + (size_t)k * HW + (size_t)g[i] * 4);
#pragma unroll
        for (int i = 0; i < 3; ++i) {
            float mm[4] = {mv[i].x, mv[i].y, mv[i].z, mv[i].w};
#pragma unroll
            for (int j = 0; j < 4; ++j) {
                float rx = P[0]*wx[i][j] + P[1]*wy[i][j] + P[2]*wz[i][j] + P[9];
                float ry = P[3]*wx[i][j] + P[4]*wy[i][j] + P[5]*wz[i][j] + P[10];
                float rz = P[6]*wx[i][j] + P[7]*wy[i][j] + P[8]*wz[i][j] + P[11];
                ax[i][j] += mm[j] * rx;
                ay[i][j] += mm[j] * ry;
                az[i][j] += mm[j] * rz;
            }
        }
    }

    const float* C = sp + 96;
#pragma unroll
    for (int i = 0; i < 3; ++i) {
        float res[8];
#pragma unroll
        for (int j = 0; j < 4; ++j) {
            float ox = C[0]*ax[i][j] + C[1]*ay[i][j] + C[2]*az[i][j] + C[9];
            float oy = C[3]*ax[i][j] + C[4]*ay[i][j] + C[5]*az[i][j] + C[10];
            float oz = C[6]*ax[i][j] + C[7]*ay[i][j] + C[8]*az[i][j] + C[11];
            res[j*2 + 0] = ox / oz - pxj[i][j];
            res[j*2 + 1] = oy / oz - pyv[i];
        }
        f32x4* o4 = (f32x4*)(out + ((size_t)b * HW + (size_t)g[i] * 4) * 2);
        f32x4 v0 = {res[0], res[1], res[2], res[3]};
        f32x4 v1 = {res[4], res[5], res[6], res[7]};
        __builtin_nontemporal_store(v0, o4);
        __builtin_nontemporal_store(v1, o4 + 1);
    }
}

extern "C" void kernel_launch(void* const* d_in, const int* in_sizes, int n_in,
                              void* d_out, int out_size, void* d_ws, size_t ws_size,
                              hipStream_t stream) {
    // inputs: im (unused), mask, depth, T, Tc — all float32
    const float* mask  = (const float*)d_in[1];
    const float* depth = (const float*)d_in[2];
    const float* T     = (const float*)d_in[3];
    const float* Tc    = (const float*)d_in[4];
    float* ws  = (float*)d_ws;
    float* out = (float*)d_out;

    k_reduce<<<dim3(NCPP, K, B), 256, 0, stream>>>(mask, depth, ws);
    k_params<<<1, 64, 0, stream>>>(T, Tc, ws);
    k_flow3<<<dim3(32, B), 384, 0, stream>>>(mask, depth, ws, out);
}